// Round 1
// baseline (351.116 us; speedup 1.0000x reference)
//
#include <hip/hip_runtime.h>

#define DNBR   16
#define INDIM  128
#define OUTDIM 64

// ---------------- Phase 1: z = h @ W_fc^T, s_src = z.a_src, s_dst = z.a_dst ----
__global__ __launch_bounds__(256) void fc_kernel(
    const float* __restrict__ h, const float* __restrict__ W_fc,
    const float* __restrict__ W_attn, float* __restrict__ z,
    float* __restrict__ s_src, float* __restrict__ s_dst, int n)
{
    // Wt[k][c] = W_fc[c][k]; lane c reads Wt[k][c]: bank = c%32 -> 2 lanes/bank, free
    __shared__ float Wt[INDIM][OUTDIM];
    for (int idx = threadIdx.x; idx < INDIM * OUTDIM; idx += 256) {
        int k = idx >> 6, c = idx & 63;
        Wt[k][c] = W_fc[c * INDIM + k];
    }
    __syncthreads();

    const int lane = threadIdx.x & 63;
    const int wid  = threadIdx.x >> 6;
    const float a_src = W_attn[lane];
    const float a_dst = W_attn[OUTDIM + lane];

    for (int node = blockIdx.x * 4 + wid; node < n; node += gridDim.x * 4) {
        const float* hrow = h + (size_t)node * INDIM;
        float acc0 = 0.f, acc1 = 0.f, acc2 = 0.f, acc3 = 0.f;
        #pragma unroll
        for (int k = 0; k < INDIM; k += 4) {
            const float4 hv = *reinterpret_cast<const float4*>(hrow + k); // wave-uniform -> broadcast
            acc0 = fmaf(hv.x, Wt[k + 0][lane], acc0);
            acc1 = fmaf(hv.y, Wt[k + 1][lane], acc1);
            acc2 = fmaf(hv.z, Wt[k + 2][lane], acc2);
            acc3 = fmaf(hv.w, Wt[k + 3][lane], acc3);
        }
        const float zc = (acc0 + acc1) + (acc2 + acc3);
        z[(size_t)node * OUTDIM + lane] = zc;

        float rs = zc * a_src, rd = zc * a_dst;
        #pragma unroll
        for (int off = 32; off >= 1; off >>= 1) {
            rs += __shfl_xor(rs, off, 64);
            rd += __shfl_xor(rd, off, 64);
        }
        if (lane == 0) { s_src[node] = rs; s_dst[node] = rd; }
    }
}

// ---------------- Phase 2: e -> entmax15 (exact, sort-based) -> out ------------
__global__ __launch_bounds__(256) void gat_kernel(
    const int* __restrict__ nbr, const float* __restrict__ wbias,
    const float* __restrict__ z, const float* __restrict__ s_src,
    const float* __restrict__ s_dst, float* __restrict__ out, int n)
{
    const int lane = threadIdx.x & 63;
    const int wid  = threadIdx.x >> 6;

    for (int node = blockIdx.x * 4 + wid; node < n; node += gridDim.x * 4) {
        // neighbor indices (wave-uniform)
        int nb[DNBR];
        const int4* nrow = reinterpret_cast<const int4*>(nbr + (size_t)node * DNBR);
        #pragma unroll
        for (int q = 0; q < 4; ++q) {
            int4 v = nrow[q];
            nb[q * 4 + 0] = v.x; nb[q * 4 + 1] = v.y;
            nb[q * 4 + 2] = v.z; nb[q * 4 + 3] = v.w;
        }

        // issue the 16 coalesced z-row gathers early; latency hides under entmax
        float zv[DNBR];
        #pragma unroll
        for (int j = 0; j < DNBR; ++j)
            zv[j] = z[(size_t)nb[j] * OUTDIM + lane];

        // e_j = leaky_relu(s_src[nb_j] + s_dst[node]) + w[node][j];  x = e/2
        const float sd = s_dst[node];
        float wv[DNBR];
        const float4* wrow = reinterpret_cast<const float4*>(wbias + (size_t)node * DNBR);
        #pragma unroll
        for (int q = 0; q < 4; ++q) {
            float4 t = wrow[q];
            wv[q * 4 + 0] = t.x; wv[q * 4 + 1] = t.y;
            wv[q * 4 + 2] = t.z; wv[q * 4 + 3] = t.w;
        }

        float x[DNBR];
        #pragma unroll
        for (int j = 0; j < DNBR; ++j) {
            float e = s_src[nb[j]] + sd;
            e = (e >= 0.f) ? e : 0.01f * e;
            e += wv[j];
            x[j] = 0.5f * e;
        }

        // subtract max
        float mx = x[0];
        #pragma unroll
        for (int j = 1; j < DNBR; ++j) mx = fmaxf(mx, x[j]);
        #pragma unroll
        for (int j = 0; j < DNBR; ++j) x[j] -= mx;

        // descending bitonic sort of a copy (fully unrolled -> static reg indices)
        float xs[DNBR];
        #pragma unroll
        for (int j = 0; j < DNBR; ++j) xs[j] = x[j];
        #pragma unroll
        for (int k = 2; k <= DNBR; k <<= 1) {
            #pragma unroll
            for (int s = k >> 1; s >= 1; s >>= 1) {
                #pragma unroll
                for (int i = 0; i < DNBR; ++i) {
                    int l = i ^ s;
                    if (l > i) {
                        const bool up = ((i & k) == 0); // descending segment
                        float a = xs[i], b = xs[l];
                        float hi = fmaxf(a, b), lo = fminf(a, b);
                        xs[i] = up ? hi : lo;
                        xs[l] = up ? lo : hi;
                    }
                }
            }
        }

        // tau_k from prefix sums; support size; tau_star
        float taus[DNBR];
        float cs = 0.f, css = 0.f;
        int supp = 0;
        #pragma unroll
        for (int k = 0; k < DNBR; ++k) {
            cs  += xs[k];
            css += xs[k] * xs[k];
            const float kk = (float)(k + 1);
            const float mean   = cs  / kk;
            const float meansq = css / kk;
            const float ssv    = kk * (meansq - mean * mean);
            const float delta  = (1.f - ssv) / kk;
            const float sq     = (delta > 0.f) ? sqrtf(delta) : 0.f;
            const float tk     = mean - sq;
            taus[k] = tk;
            supp += (tk <= xs[k]) ? 1 : 0;
        }
        float tau_star = taus[0];
        #pragma unroll
        for (int k = 1; k < DNBR; ++k)
            tau_star = (supp - 1 == k) ? taus[k] : tau_star;

        // out[node][lane] = sum_j (max(x_j - tau, 0))^2 * z[nb_j][lane]
        float acc = 0.f;
        #pragma unroll
        for (int j = 0; j < DNBR; ++j) {
            const float y = fmaxf(x[j] - tau_star, 0.f);
            acc = fmaf(y * y, zv[j], acc);
        }
        out[(size_t)node * OUTDIM + lane] = acc;
    }
}

extern "C" void kernel_launch(void* const* d_in, const int* in_sizes, int n_in,
                              void* d_out, int out_size, void* d_ws, size_t ws_size,
                              hipStream_t stream) {
    const float* h      = (const float*)d_in[0];
    const int*   nbr    = (const int*)  d_in[1];
    const float* wbias  = (const float*)d_in[2];
    const float* W_fc   = (const float*)d_in[3];
    const float* W_attn = (const float*)d_in[4];
    float* out = (float*)d_out;

    const int n = in_sizes[0] / INDIM;   // 100000

    float* z     = (float*)d_ws;         // n*64
    float* s_src = z + (size_t)n * OUTDIM;
    float* s_dst = s_src + n;

    fc_kernel<<<1024, 256, 0, stream>>>(h, W_fc, W_attn, z, s_src, s_dst, n);
    gat_kernel<<<2048, 256, 0, stream>>>(nbr, wbias, z, s_src, s_dst, out, n);
}

// Round 2
// 143.507 us; speedup vs baseline: 2.4467x; 2.4467x over previous
//
#include <hip/hip_runtime.h>

#define DNBR   16
#define INDIM  128
#define OUTDIM 64
#define BM 64
#define BKT 64

// ---------------- exact entmax15 over 16 values (alpha weights = y^2) ---------
__device__ __forceinline__ void entmax15_weights(float x[DNBR], float wout[DNBR]) {
    // subtract max
    float mx = x[0];
    #pragma unroll
    for (int j = 1; j < DNBR; ++j) mx = fmaxf(mx, x[j]);
    #pragma unroll
    for (int j = 0; j < DNBR; ++j) x[j] -= mx;

    // descending bitonic sort of a copy (fully unrolled -> static reg indices)
    float xs[DNBR];
    #pragma unroll
    for (int j = 0; j < DNBR; ++j) xs[j] = x[j];
    #pragma unroll
    for (int k = 2; k <= DNBR; k <<= 1) {
        #pragma unroll
        for (int s = k >> 1; s >= 1; s >>= 1) {
            #pragma unroll
            for (int i = 0; i < DNBR; ++i) {
                int l = i ^ s;
                if (l > i) {
                    const bool up = ((i & k) == 0);
                    float a = xs[i], b = xs[l];
                    float hi = fmaxf(a, b), lo = fminf(a, b);
                    xs[i] = up ? hi : lo;
                    xs[l] = up ? lo : hi;
                }
            }
        }
    }

    float taus[DNBR];
    float cs = 0.f, css = 0.f;
    int supp = 0;
    #pragma unroll
    for (int k = 0; k < DNBR; ++k) {
        cs  += xs[k];
        css += xs[k] * xs[k];
        const float kk = (float)(k + 1);
        const float mean   = cs  / kk;
        const float meansq = css / kk;
        const float ssv    = kk * (meansq - mean * mean);
        const float delta  = (1.f - ssv) / kk;
        const float sq     = (delta > 0.f) ? sqrtf(delta) : 0.f;
        taus[k] = mean - sq;
        supp += (taus[k] <= xs[k]) ? 1 : 0;
    }
    float tau_star = taus[0];
    #pragma unroll
    for (int k = 1; k < DNBR; ++k)
        tau_star = (supp - 1 == k) ? taus[k] : tau_star;

    #pragma unroll
    for (int j = 0; j < DNBR; ++j) {
        const float y = fmaxf(x[j] - tau_star, 0.f);
        wout[j] = y * y;
    }
}

// ---------------- Phase 1: register-blocked GEMM z = h @ W_fc^T + s epilogue ---
__global__ __launch_bounds__(256) void fc_gemm(
    const float* __restrict__ h, const float* __restrict__ W_fc,
    const float* __restrict__ W_attn, float* __restrict__ z,
    float* __restrict__ s_src, float* __restrict__ s_dst, int n)
{
    __shared__ float As[BKT][BM + 1];      // h^T tile: [k][row]
    __shared__ float Bs[BKT][OUTDIM + 1];  // W^T tile: [k][col]

    const int tid = threadIdx.x;
    const int tx = tid & 15, ty = tid >> 4;      // 16 x 16 threads
    const int row0 = blockIdx.x * BM;

    float acc[4][4];
    #pragma unroll
    for (int i = 0; i < 4; ++i)
        #pragma unroll
        for (int j = 0; j < 4; ++j) acc[i][j] = 0.f;

    for (int kt = 0; kt < INDIM; kt += BKT) {
        // cooperative load + transpose into LDS (2-way bank aliasing only)
        #pragma unroll
        for (int i = 0; i < 4; ++i) {
            const int f  = tid + 256 * i;   // float4 index 0..1023
            const int r  = f >> 4;          // 0..63
            const int k4 = f & 15;          // 0..15
            float4 v = make_float4(0.f, 0.f, 0.f, 0.f);
            if (row0 + r < n)
                v = *reinterpret_cast<const float4*>(&h[(size_t)(row0 + r) * INDIM + kt + 4 * k4]);
            As[4 * k4 + 0][r] = v.x; As[4 * k4 + 1][r] = v.y;
            As[4 * k4 + 2][r] = v.z; As[4 * k4 + 3][r] = v.w;
            const float4 wv = *reinterpret_cast<const float4*>(&W_fc[(size_t)r * INDIM + kt + 4 * k4]);
            Bs[4 * k4 + 0][r] = wv.x; Bs[4 * k4 + 1][r] = wv.y;
            Bs[4 * k4 + 2][r] = wv.z; Bs[4 * k4 + 3][r] = wv.w;
        }
        __syncthreads();
        #pragma unroll
        for (int k = 0; k < BKT; ++k) {
            const float4 av = *reinterpret_cast<const float4*>(&As[k][4 * ty]);
            const float4 bv = *reinterpret_cast<const float4*>(&Bs[k][4 * tx]);
            const float a[4] = {av.x, av.y, av.z, av.w};
            const float b[4] = {bv.x, bv.y, bv.z, bv.w};
            #pragma unroll
            for (int i = 0; i < 4; ++i)
                #pragma unroll
                for (int j = 0; j < 4; ++j)
                    acc[i][j] = fmaf(a[i], b[j], acc[i][j]);
        }
        __syncthreads();
    }

    // store z (coalesced float4) + attention-score partials
    const float4 asrc = *reinterpret_cast<const float4*>(&W_attn[4 * tx]);
    const float4 adst = *reinterpret_cast<const float4*>(&W_attn[OUTDIM + 4 * tx]);
    float* red = &As[0][0];   // reuse: [0..1023] = src partials, [1024..2047] = dst
    #pragma unroll
    for (int i = 0; i < 4; ++i) {
        const int row = 4 * ty + i;
        if (row0 + row < n) {
            float4 zr = make_float4(acc[i][0], acc[i][1], acc[i][2], acc[i][3]);
            *reinterpret_cast<float4*>(&z[(size_t)(row0 + row) * OUTDIM + 4 * tx]) = zr;
        }
        const float ps = acc[i][0] * asrc.x + acc[i][1] * asrc.y + acc[i][2] * asrc.z + acc[i][3] * asrc.w;
        const float pd = acc[i][0] * adst.x + acc[i][1] * adst.y + acc[i][2] * adst.z + acc[i][3] * adst.w;
        red[row * 16 + tx]        = ps;
        red[1024 + row * 16 + tx] = pd;
    }
    __syncthreads();
    if (tid < 64 && row0 + tid < n) {
        float ss = 0.f, dd = 0.f;
        #pragma unroll
        for (int t = 0; t < 16; ++t) {
            ss += red[tid * 16 + t];
            dd += red[1024 + tid * 16 + t];
        }
        s_src[row0 + tid] = ss;
        s_dst[row0 + tid] = dd;
    }
}

// ---------------- Phase 2: one THREAD per node computes entmax weights --------
__global__ __launch_bounds__(256) void alpha_kernel(
    const int* __restrict__ nbr, const float* __restrict__ wbias,
    const float* __restrict__ s_src, const float* __restrict__ s_dst,
    float* __restrict__ alpha, int n)
{
    const int node = blockIdx.x * 256 + threadIdx.x;
    if (node >= n) return;

    const int4* nrow = reinterpret_cast<const int4*>(nbr + (size_t)node * DNBR);
    const float4* wrow = reinterpret_cast<const float4*>(wbias + (size_t)node * DNBR);
    const float sd = s_dst[node];

    float x[DNBR];
    #pragma unroll
    for (int q = 0; q < 4; ++q) {
        const int4 v = nrow[q];
        const float4 t = wrow[q];
        const int nb4[4] = {v.x, v.y, v.z, v.w};
        const float w4[4] = {t.x, t.y, t.z, t.w};
        #pragma unroll
        for (int j = 0; j < 4; ++j) {
            float e = s_src[nb4[j]] + sd;
            e = (e >= 0.f) ? e : 0.01f * e;
            x[q * 4 + j] = 0.5f * (e + w4[j]);
        }
    }

    float wts[DNBR];
    entmax15_weights(x, wts);

    float4* arow = reinterpret_cast<float4*>(alpha + (size_t)node * DNBR);
    #pragma unroll
    for (int q = 0; q < 4; ++q)
        arow[q] = make_float4(wts[q * 4 + 0], wts[q * 4 + 1], wts[q * 4 + 2], wts[q * 4 + 3]);
}

// ---------------- Phase 3: wave per node: gather z rows, weight, sum ----------
__global__ __launch_bounds__(256) void out_kernel(
    const int* __restrict__ nbr, const float* __restrict__ alpha,
    const float* __restrict__ z, float* __restrict__ out, int n)
{
    const int lane = threadIdx.x & 63;
    const int wid  = threadIdx.x >> 6;

    for (int node = blockIdx.x * 4 + wid; node < n; node += gridDim.x * 4) {
        int nb[DNBR];
        const int4* nrow = reinterpret_cast<const int4*>(nbr + (size_t)node * DNBR);
        #pragma unroll
        for (int q = 0; q < 4; ++q) {
            const int4 v = nrow[q];
            nb[q * 4 + 0] = v.x; nb[q * 4 + 1] = v.y;
            nb[q * 4 + 2] = v.z; nb[q * 4 + 3] = v.w;
        }
        float aw[DNBR];
        const float4* arow = reinterpret_cast<const float4*>(alpha + (size_t)node * DNBR);
        #pragma unroll
        for (int q = 0; q < 4; ++q) {
            const float4 t = arow[q];
            aw[q * 4 + 0] = t.x; aw[q * 4 + 1] = t.y;
            aw[q * 4 + 2] = t.z; aw[q * 4 + 3] = t.w;
        }
        float acc = 0.f;
        #pragma unroll
        for (int j = 0; j < DNBR; ++j)
            acc = fmaf(aw[j], z[(size_t)nb[j] * OUTDIM + lane], acc);
        out[(size_t)node * OUTDIM + lane] = acc;
    }
}

// ---------------- Fallback (round-1 style) if workspace is too small ----------
__global__ __launch_bounds__(256) void gat_fallback(
    const int* __restrict__ nbr, const float* __restrict__ wbias,
    const float* __restrict__ z, const float* __restrict__ s_src,
    const float* __restrict__ s_dst, float* __restrict__ out, int n)
{
    const int lane = threadIdx.x & 63;
    const int wid  = threadIdx.x >> 6;

    for (int node = blockIdx.x * 4 + wid; node < n; node += gridDim.x * 4) {
        int nb[DNBR];
        const int4* nrow = reinterpret_cast<const int4*>(nbr + (size_t)node * DNBR);
        #pragma unroll
        for (int q = 0; q < 4; ++q) {
            const int4 v = nrow[q];
            nb[q * 4 + 0] = v.x; nb[q * 4 + 1] = v.y;
            nb[q * 4 + 2] = v.z; nb[q * 4 + 3] = v.w;
        }
        float zv[DNBR];
        #pragma unroll
        for (int j = 0; j < DNBR; ++j)
            zv[j] = z[(size_t)nb[j] * OUTDIM + lane];

        const float sd = s_dst[node];
        float x[DNBR];
        const float4* wrow = reinterpret_cast<const float4*>(wbias + (size_t)node * DNBR);
        #pragma unroll
        for (int q = 0; q < 4; ++q) {
            const float4 t = wrow[q];
            const float w4[4] = {t.x, t.y, t.z, t.w};
            #pragma unroll
            for (int j = 0; j < 4; ++j) {
                float e = s_src[nb[q * 4 + j]] + sd;
                e = (e >= 0.f) ? e : 0.01f * e;
                x[q * 4 + j] = 0.5f * (e + w4[j]);
            }
        }
        float wts[DNBR];
        entmax15_weights(x, wts);
        float acc = 0.f;
        #pragma unroll
        for (int j = 0; j < DNBR; ++j)
            acc = fmaf(wts[j], zv[j], acc);
        out[(size_t)node * OUTDIM + lane] = acc;
    }
}

extern "C" void kernel_launch(void* const* d_in, const int* in_sizes, int n_in,
                              void* d_out, int out_size, void* d_ws, size_t ws_size,
                              hipStream_t stream) {
    const float* h      = (const float*)d_in[0];
    const int*   nbr    = (const int*)  d_in[1];
    const float* wbias  = (const float*)d_in[2];
    const float* W_fc   = (const float*)d_in[3];
    const float* W_attn = (const float*)d_in[4];
    float* out = (float*)d_out;

    const int n = in_sizes[0] / INDIM;   // 100000

    float* z     = (float*)d_ws;                      // n*64
    float* s_src = z + (size_t)n * OUTDIM;            // n
    float* s_dst = s_src + n;                         // n
    float* alpha = s_dst + n;                         // n*16

    const size_t need_full = (size_t)n * (OUTDIM + 2 + DNBR) * sizeof(float);

    const int fc_blocks = (n + BM - 1) / BM;
    fc_gemm<<<fc_blocks, 256, 0, stream>>>(h, W_fc, W_attn, z, s_src, s_dst, n);

    if (ws_size >= need_full) {
        alpha_kernel<<<(n + 255) / 256, 256, 0, stream>>>(nbr, wbias, s_src, s_dst, alpha, n);
        out_kernel<<<2048, 256, 0, stream>>>(nbr, alpha, z, out, n);
    } else {
        gat_fallback<<<2048, 256, 0, stream>>>(nbr, wbias, z, s_src, s_dst, out, n);
    }
}

// Round 3
// 92.559 us; speedup vs baseline: 3.7934x; 1.5504x over previous
//
#include <hip/hip_runtime.h>
#include <hip/hip_bf16.h>

#define DNBR   16
#define INDIM  128
#define OUTDIM 64

typedef __attribute__((ext_vector_type(8))) short bf16x8;
typedef __attribute__((ext_vector_type(4))) float f32x4;

__device__ __forceinline__ short f2bf(float f) {
    union { float f; unsigned u; } v; v.f = f;
    const unsigned r = v.u + 0x7FFFu + ((v.u >> 16) & 1u);   // RNE
    return (short)(r >> 16);
}

// ---------------- Phase 1: z = h @ W_fc^T via bf16 MFMA, + s_src/s_dst -------
// One wave = 16 rows x 64 cols. No LDS, no barriers.
// A,B packed with the SAME k-bijection (k = kk*32 + lg*8 + j) -> layout-proof.
__global__ __launch_bounds__(256) void fc_mfma(
    const float* __restrict__ h, const float* __restrict__ W_fc,
    const float* __restrict__ W_attn, __hip_bfloat16* __restrict__ zb,
    float* __restrict__ s_src, float* __restrict__ s_dst, int n)
{
    const int lane  = threadIdx.x & 63;
    const int wid   = threadIdx.x >> 6;
    const int node0 = blockIdx.x * 64 + wid * 16;
    if (node0 >= n) return;
    const int lm = lane & 15;   // row (A) / col (B,C)
    const int lg = lane >> 4;   // k-group

    // B fragments: B[k][c] = W_fc[c][k]; 4 col-tiles x 4 k-chunks (cached 32KB)
    bf16x8 bfrag[4][4];
    #pragma unroll
    for (int ct = 0; ct < 4; ++ct) {
        const float* wr = W_fc + (size_t)(ct * 16 + lm) * INDIM;
        #pragma unroll
        for (int kk = 0; kk < 4; ++kk) {
            const float4 w0 = *reinterpret_cast<const float4*>(wr + kk * 32 + lg * 8);
            const float4 w1 = *reinterpret_cast<const float4*>(wr + kk * 32 + lg * 8 + 4);
            bfrag[ct][kk][0] = f2bf(w0.x); bfrag[ct][kk][1] = f2bf(w0.y);
            bfrag[ct][kk][2] = f2bf(w0.z); bfrag[ct][kk][3] = f2bf(w0.w);
            bfrag[ct][kk][4] = f2bf(w1.x); bfrag[ct][kk][5] = f2bf(w1.y);
            bfrag[ct][kk][6] = f2bf(w1.z); bfrag[ct][kk][7] = f2bf(w1.w);
        }
    }

    f32x4 acc[4];
    #pragma unroll
    for (int ct = 0; ct < 4; ++ct) acc[ct] = (f32x4){0.f, 0.f, 0.f, 0.f};

    // A: row = node0 + lm (clamped; garbage rows never stored/referenced)
    const int arow = (node0 + lm < n) ? (node0 + lm) : (n - 1);
    const float* hr = h + (size_t)arow * INDIM;
    #pragma unroll
    for (int kk = 0; kk < 4; ++kk) {
        const float4 a0 = *reinterpret_cast<const float4*>(hr + kk * 32 + lg * 8);
        const float4 a1 = *reinterpret_cast<const float4*>(hr + kk * 32 + lg * 8 + 4);
        bf16x8 af;
        af[0] = f2bf(a0.x); af[1] = f2bf(a0.y); af[2] = f2bf(a0.z); af[3] = f2bf(a0.w);
        af[4] = f2bf(a1.x); af[5] = f2bf(a1.y); af[6] = f2bf(a1.z); af[7] = f2bf(a1.w);
        #pragma unroll
        for (int ct = 0; ct < 4; ++ct)
            acc[ct] = __builtin_amdgcn_mfma_f32_16x16x32_bf16(af, bfrag[ct][kk], acc[ct], 0, 0, 0);
    }

    // Epilogue: z store (bf16) + attention-score partials, reduce over lm
    float ps[4] = {0.f, 0.f, 0.f, 0.f};
    float pd[4] = {0.f, 0.f, 0.f, 0.f};
    unsigned short* zbs = reinterpret_cast<unsigned short*>(zb);
    #pragma unroll
    for (int ct = 0; ct < 4; ++ct) {
        const float as = W_attn[ct * 16 + lm];
        const float ad = W_attn[OUTDIM + ct * 16 + lm];
        #pragma unroll
        for (int r = 0; r < 4; ++r) {
            const float v = acc[ct][r];                 // C[(lg*4+r)][ct*16+lm]
            const int grow = node0 + lg * 4 + r;
            if (grow < n)
                zbs[(size_t)grow * OUTDIM + ct * 16 + lm] = (unsigned short)f2bf(v);
            ps[r] = fmaf(v, as, ps[r]);
            pd[r] = fmaf(v, ad, pd[r]);
        }
    }
    #pragma unroll
    for (int off = 1; off < 16; off <<= 1) {
        #pragma unroll
        for (int r = 0; r < 4; ++r) {
            ps[r] += __shfl_xor(ps[r], off, 64);
            pd[r] += __shfl_xor(pd[r], off, 64);
        }
    }
    if (lm == 0) {
        #pragma unroll
        for (int r = 0; r < 4; ++r) {
            const int grow = node0 + lg * 4 + r;
            if (grow < n) { s_src[grow] = ps[r]; s_dst[grow] = pd[r]; }
        }
    }
}

// ---------------- exact entmax15 over 16 values (weights = y^2) ---------------
__device__ __forceinline__ void entmax15_weights(float x[DNBR], float wout[DNBR]) {
    float mx = x[0];
    #pragma unroll
    for (int j = 1; j < DNBR; ++j) mx = fmaxf(mx, x[j]);
    #pragma unroll
    for (int j = 0; j < DNBR; ++j) x[j] -= mx;

    float xs[DNBR];
    #pragma unroll
    for (int j = 0; j < DNBR; ++j) xs[j] = x[j];
    #pragma unroll
    for (int k = 2; k <= DNBR; k <<= 1) {
        #pragma unroll
        for (int s = k >> 1; s >= 1; s >>= 1) {
            #pragma unroll
            for (int i = 0; i < DNBR; ++i) {
                int l = i ^ s;
                if (l > i) {
                    const bool up = ((i & k) == 0);
                    float a = xs[i], b = xs[l];
                    float hi = fmaxf(a, b), lo = fminf(a, b);
                    xs[i] = up ? hi : lo;
                    xs[l] = up ? lo : hi;
                }
            }
        }
    }

    float taus[DNBR];
    float cs = 0.f, css = 0.f;
    int supp = 0;
    #pragma unroll
    for (int k = 0; k < DNBR; ++k) {
        cs  += xs[k];
        css += xs[k] * xs[k];
        const float kk = (float)(k + 1);
        const float mean   = cs  / kk;
        const float meansq = css / kk;
        const float ssv    = kk * (meansq - mean * mean);
        const float delta  = (1.f - ssv) / kk;
        const float sq     = (delta > 0.f) ? sqrtf(delta) : 0.f;
        taus[k] = mean - sq;
        supp += (taus[k] <= xs[k]) ? 1 : 0;
    }
    float tau_star = taus[0];
    #pragma unroll
    for (int k = 1; k < DNBR; ++k)
        tau_star = (supp - 1 == k) ? taus[k] : tau_star;

    #pragma unroll
    for (int j = 0; j < DNBR; ++j) {
        const float y = fmaxf(x[j] - tau_star, 0.f);
        wout[j] = y * y;
    }
}

// ---------------- Phase 2: one thread per node -> alpha[n][16] ----------------
__global__ __launch_bounds__(256) void alpha_kernel(
    const int* __restrict__ nbr, const float* __restrict__ wbias,
    const float* __restrict__ s_src, const float* __restrict__ s_dst,
    float* __restrict__ alpha, int n)
{
    const int node = blockIdx.x * 256 + threadIdx.x;
    if (node >= n) return;

    const int4*   nrow = reinterpret_cast<const int4*>(nbr + (size_t)node * DNBR);
    const float4* wrow = reinterpret_cast<const float4*>(wbias + (size_t)node * DNBR);
    const float sd = s_dst[node];

    float x[DNBR];
    #pragma unroll
    for (int q = 0; q < 4; ++q) {
        const int4 v   = nrow[q];
        const float4 t = wrow[q];
        const int   nb4[4] = {v.x, v.y, v.z, v.w};
        const float w4[4]  = {t.x, t.y, t.z, t.w};
        #pragma unroll
        for (int j = 0; j < 4; ++j) {
            float e = s_src[nb4[j]] + sd;
            e = (e >= 0.f) ? e : 0.01f * e;
            x[q * 4 + j] = 0.5f * (e + w4[j]);
        }
    }

    float wts[DNBR];
    entmax15_weights(x, wts);

    float4* arow = reinterpret_cast<float4*>(alpha + (size_t)node * DNBR);
    #pragma unroll
    for (int q = 0; q < 4; ++q)
        arow[q] = make_float4(wts[q * 4 + 0], wts[q * 4 + 1], wts[q * 4 + 2], wts[q * 4 + 3]);
}

// ---------------- Phase 3: wave per node: gather bf16 z rows, weight, sum -----
__global__ __launch_bounds__(256) void out_kernel(
    const int* __restrict__ nbr, const float* __restrict__ alpha,
    const __hip_bfloat16* __restrict__ zb, float* __restrict__ out, int n)
{
    const int lane = threadIdx.x & 63;
    const int wid  = threadIdx.x >> 6;

    for (int node = blockIdx.x * 4 + wid; node < n; node += gridDim.x * 4) {
        int nb[DNBR];
        const int4* nrow = reinterpret_cast<const int4*>(nbr + (size_t)node * DNBR);
        #pragma unroll
        for (int q = 0; q < 4; ++q) {
            const int4 v = nrow[q];
            nb[q * 4 + 0] = v.x; nb[q * 4 + 1] = v.y;
            nb[q * 4 + 2] = v.z; nb[q * 4 + 3] = v.w;
        }
        float aw[DNBR];
        const float4* arow = reinterpret_cast<const float4*>(alpha + (size_t)node * DNBR);
        #pragma unroll
        for (int q = 0; q < 4; ++q) {
            const float4 t = arow[q];
            aw[q * 4 + 0] = t.x; aw[q * 4 + 1] = t.y;
            aw[q * 4 + 2] = t.z; aw[q * 4 + 3] = t.w;
        }
        float acc = 0.f;
        #pragma unroll
        for (int j = 0; j < DNBR; ++j)
            acc = fmaf(aw[j], __bfloat162float(zb[(size_t)nb[j] * OUTDIM + lane]), acc);
        out[(size_t)node * OUTDIM + lane] = acc;
    }
}

extern "C" void kernel_launch(void* const* d_in, const int* in_sizes, int n_in,
                              void* d_out, int out_size, void* d_ws, size_t ws_size,
                              hipStream_t stream) {
    const float* h      = (const float*)d_in[0];
    const int*   nbr    = (const int*)  d_in[1];
    const float* wbias  = (const float*)d_in[2];
    const float* W_fc   = (const float*)d_in[3];
    const float* W_attn = (const float*)d_in[4];
    float* out = (float*)d_out;

    const int n = in_sizes[0] / INDIM;   // 100000

    // workspace: zb (n*64 bf16) | s_src (n f32) | s_dst (n f32) | alpha (n*16 f32)
    __hip_bfloat16* zb = (__hip_bfloat16*)d_ws;
    float* s_src = (float*)((char*)d_ws + (size_t)n * OUTDIM * sizeof(__hip_bfloat16));
    float* s_dst = s_src + n;
    float* alpha = s_dst + n;

    const int fc_blocks = (n + 63) / 64;
    fc_mfma<<<fc_blocks, 256, 0, stream>>>(h, W_fc, W_attn, zb, s_src, s_dst, n);
    alpha_kernel<<<(n + 255) / 256, 256, 0, stream>>>(nbr, wbias, s_src, s_dst, alpha, n);
    out_kernel<<<2048, 256, 0, stream>>>(nbr, alpha, zb, out, n);
}